// Round 11
// baseline (127.252 us; speedup 1.0000x reference)
//
#include <hip/hip_runtime.h>

// Problem constants: B=4, h=w=z=16 -> N=4096, C=128, Cq=16
#define NB     4
#define NN     4096
#define NC     128
#define NCQ    16
#define NROWS  (NB * NN)      // 16384
#define NSLICE 4
#define NIT    (NN / 64 / NSLICE)   // 16 iterations of 64 keys per slice

typedef __attribute__((ext_vector_type(8)))  __bf16 bf16x8;
typedef __attribute__((ext_vector_type(4)))  float  f32x4;
typedef __attribute__((ext_vector_type(16))) float  f32x16;

#define MFMA16(a,b,c) __builtin_amdgcn_mfma_f32_16x16x32_bf16((a),(b),(c),0,0,0)
#define MFMA32(a,b,c) __builtin_amdgcn_mfma_f32_32x32x16_bf16((a),(b),(c),0,0,0)
#define LOG2E 1.44269504f

__device__ __forceinline__ f32x16 zero16() {
    f32x16 v;
    #pragma unroll
    for (int i = 0; i < 16; ++i) v[i] = 0.f;
    return v;
}

// Swizzled fragment layouts (lane = lh*32 + l31):
//  qswz: [batch][qb32][lane][8]  elem j = (LOG2E * Q)[32*qb32 + l31][ch = 8*lh + j]
//  kswz: [batch][kb32][lane][8]  elem j = K[32*kb32 + l31][ch = 8*lh + j]
//  vswz: [batch][kb16][cg][lane][8]
//        elem j = V^T[ch = 32*cg + l31][key = 16*kb16 + 4*lh + (j&3) + 8*(j>>2)]

// ---------------------------------------------------------------------------
// Kernel 0: W^T precompute -> wtg[160][128] bf16.
// ---------------------------------------------------------------------------
__global__ void wtrans_kernel(const float* __restrict__ Wb,
                              const float* __restrict__ Wc,
                              const float* __restrict__ Wd,
                              __bf16* __restrict__ wtg)
{
    int oc = blockIdx.x;      // 0..159
    int ch = threadIdx.x;     // 0..127
    float v;
    if      (oc < 16) v = Wb[ch * 16  + oc];
    else if (oc < 32) v = Wc[ch * 16  + (oc - 16)];
    else              v = Wd[ch * 128 + (oc - 32)];
    wtg[oc * 128 + ch] = (__bf16)v;
}

// ---------------------------------------------------------------------------
// Kernel 1: projections via MFMA (verified R5-R10 structure; qswz pre-scaled
// by LOG2E so attn's exp needs no multiply).
// ---------------------------------------------------------------------------
__global__ __launch_bounds__(256) void proj_kernel(
    const float* __restrict__ x, const __bf16* __restrict__ wtg,
    __bf16* __restrict__ qswz, __bf16* __restrict__ kswz, __bf16* __restrict__ vswz)
{
    __shared__ __align__(16) __bf16 xsh[32 * 136];   // [row][136]
    __shared__ __align__(16) __bf16 wt [160 * 136];  // [outcol][136]
    __shared__ __align__(16) float  osb[4][16 * 17]; // per-wave transpose buffer

    const int  t    = threadIdx.x;
    const int  lane = t & 63, w = t >> 6;
    const int  q16  = lane & 15, quad = lane >> 4;
    const long row0 = (long)blockIdx.x * 32;
    const int  batch = (int)(row0 >> 12);
    const int  nloc  = (int)(row0 & 4095);
    const int  rh   = w & 1;
    const int  og   = (w >> 1) * 5;

    #pragma unroll
    for (int i = 0; i < 4; ++i) {
        int idx = t + 256 * i;           // < 1024
        int r = idx >> 5, c4 = (idx & 31) * 4;
        float4 xv = *(const float4*)&x[(row0 + r) * NC + c4];
        union { __bf16 h[4]; uint2 u; } cv;
        cv.h[0] = (__bf16)xv.x; cv.h[1] = (__bf16)xv.y;
        cv.h[2] = (__bf16)xv.z; cv.h[3] = (__bf16)xv.w;
        *(uint2*)&xsh[r * 136 + c4] = cv.u;
    }
    #pragma unroll
    for (int i = 0; i < 10; ++i) {
        int idx = t + 256 * i;           // < 2560
        int oc = idx >> 4, seg = idx & 15;
        *(uint4*)&wt[oc * 136 + seg * 8] = ((const uint4*)wtg)[idx];
    }
    __syncthreads();

    bf16x8 xf[4];
    #pragma unroll
    for (int kc = 0; kc < 4; ++kc)
        xf[kc] = *(const bf16x8*)&xsh[(rh * 16 + q16) * 136 + kc * 32 + quad * 8];

    float* osw = osb[w];
    #pragma unroll
    for (int oc_t = 0; oc_t < 5; ++oc_t) {
        const int oset = og + oc_t;
        f32x4 acc = {0.f, 0.f, 0.f, 0.f};
        #pragma unroll
        for (int kc = 0; kc < 4; ++kc) {
            bf16x8 wf = *(const bf16x8*)&wt[(oset * 16 + q16) * 136 + kc * 32 + quad * 8];
            acc = MFMA16(wf, xf[kc], acc);   // D'[oc][row]
        }
        #pragma unroll
        for (int r = 0; r < 4; ++r)
            osw[(quad * 4 + r) * 17 + q16] = acc[r];   // osb[oc16][xrow16]

        if (oset >= 2) {
            int ch_l = lane & 15, lh_t = (lane >> 4) & 1, jh = lane >> 5;
            union { __bf16 h[4]; uint2 u; } cv;
            #pragma unroll
            for (int u2 = 0; u2 < 4; ++u2)
                cv.h[u2] = (__bf16)osw[ch_l * 17 + 8 * jh + 4 * lh_t + u2];
            int kb16 = (nloc >> 4) + rh;
            int cg   = (oset - 2) >> 1;
            int l31v = ((oset - 2) & 1) * 16 + ch_l;
            size_t off = ((((size_t)batch * 256 + kb16) * 4 + cg) << 9)
                       + (size_t)(lh_t * 32 + l31v) * 8 + jh * 4;
            *(uint2*)&vswz[off] = cv.u;
        } else if (lane < 32) {
            int xr = lane & 15, lh_t = lane >> 4;
            const float qsc = (oset == 0) ? LOG2E : 1.f;  // fold log2e into Q
            union { __bf16 h[8]; uint4 u; } cv;
            #pragma unroll
            for (int j = 0; j < 8; ++j)
                cv.h[j] = (__bf16)(osw[(8 * lh_t + j) * 17 + xr] * qsc);
            size_t off = ((((size_t)batch * 128 + (nloc >> 5)) * 64)
                       + (size_t)(lh_t * 32 + rh * 16 + xr)) * 8;
            __bf16* dst = (oset == 0) ? qswz : kswz;
            *(uint4*)&dst[off] = cv.u;
        }
    }
}

// ---------------------------------------------------------------------------
// Kernel 2: flash attention — 64-QUERY waves (two q-blocks share every V
// fragment: V traffic halved, 20 MFMA per 10 loads/iter). 4 independent
// waves per block (h = w&1 channel half, slice = sp*2 + (w>>1)), split-K x4,
// XCD swizzle (bid&7 -> batch, slice-pair => V/K/Q L2-resident). Full
// next-iter V double-buffer, K prefetch 1 ahead, 4 S-MFMAs at loop bottom.
// Lean softmax: exp2 direct (Q pre-scaled), truncating bf16 pack.
// No LDS, no barriers, no atomics. Live set ~245 regs -> (256,2) cap.
// ---------------------------------------------------------------------------
__global__ __launch_bounds__(256, 2) void attn_kernel(
    const __bf16* __restrict__ qswz, const __bf16* __restrict__ kswz,
    const __bf16* __restrict__ vswz, __bf16* __restrict__ Opart,
    float* __restrict__ lws)
{
    const int t    = threadIdx.x;
    const int lane = t & 63, w = t >> 6;
    const int l31 = lane & 31, lh = lane >> 5;
    const int bid   = blockIdx.x;
    const int xcd   = bid & 7;
    const int batch = xcd >> 1;              // constant per XCD
    const int sp    = xcd & 1;               // slice-pair, constant per XCD
    const int qb64  = bid >> 3;              // 0..63
    const int h     = w & 1;                 // channel half
    const int slice = sp * 2 + (w >> 1);     // 0..3
    const int ks0   = slice * (64 * NIT);
    const int qb32a = qb64 * 2, qb32b = qb64 * 2 + 1;

    // Q B-frags, fixed: n = q = 32*qb32 + l31, k = ch = 8*lh + j
    const bf16x8 qf0 = *(const bf16x8*)
        &qswz[(((size_t)batch * 128 + qb32a) * 64 + lane) * 8];
    const bf16x8 qf1 = *(const bf16x8*)
        &qswz[(((size_t)batch * 128 + qb32b) * 64 + lane) * 8];

    const __bf16* kptr = kswz + ((size_t)batch * 128 + (ks0 >> 5)) * 512 + lane * 8;
    const __bf16* vptr = vswz + ((size_t)batch * 256 + (ks0 >> 4)) * 2048
                       + h * 1024 + lane * 8;

    f32x16 O00 = zero16(), O01 = zero16(), O10 = zero16(), O11 = zero16();
    float l0 = 0.f, l1 = 0.f;

    bf16x8 kf0 = *(const bf16x8*)(kptr);
    bf16x8 kf1 = *(const bf16x8*)(kptr + 512);
    bf16x8 va[8], vb[8];
    #pragma unroll
    for (int b = 0; b < 4; ++b) {           // iter-0 V frags (ct = 0,1)
        va[2*b]     = *(const bf16x8*)(vptr + (size_t)(b * 4)     * 512);
        va[2*b + 1] = *(const bf16x8*)(vptr + (size_t)(b * 4 + 1) * 512);
    }
    f32x16 S0 = MFMA32(kf0, qf0, zero16());   // S^T[kb0][qb a]
    f32x16 S1 = MFMA32(kf1, qf0, zero16());   // S^T[kb1][qb a]
    f32x16 S2 = MFMA32(kf0, qf1, zero16());   // S^T[kb0][qb b]
    f32x16 S3 = MFMA32(kf1, qf1, zero16());   // S^T[kb1][qb b]

#define ATTN_BODY(IT, CUR, NXT)                                               \
    {                                                                         \
        const int itn = ((IT) + 1 < NIT) ? (IT) + 1 : (IT);                   \
        kf0 = *(const bf16x8*)(kptr + (size_t)itn * 1024);                    \
        kf1 = *(const bf16x8*)(kptr + (size_t)itn * 1024 + 512);              \
        _Pragma("unroll")                                                     \
        for (int b = 0; b < 4; ++b) {                                         \
            NXT[2*b]     = *(const bf16x8*)(vptr + (size_t)((itn*4+b)*4)*512);\
            NXT[2*b + 1] = *(const bf16x8*)(vptr + (size_t)((itn*4+b)*4+1)*512);\
        }                                                                     \
        union { uint32_t u32[16]; bf16x8 f[4]; } pk0, pk1;                    \
        _Pragma("unroll")                                                     \
        for (int i = 0; i < 8; ++i) {                                         \
            float a0 = __builtin_exp2f(S0[2*i]);                              \
            float a1 = __builtin_exp2f(S0[2*i+1]);                            \
            float a2 = __builtin_exp2f(S1[2*i]);                              \
            float a3 = __builtin_exp2f(S1[2*i+1]);                            \
            float b0 = __builtin_exp2f(S2[2*i]);                              \
            float b1 = __builtin_exp2f(S2[2*i+1]);                            \
            float b2 = __builtin_exp2f(S3[2*i]);                              \
            float b3 = __builtin_exp2f(S3[2*i+1]);                            \
            l0 += (a0 + a1) + (a2 + a3);                                      \
            l1 += (b0 + b1) + (b2 + b3);                                      \
            uint32_t ua0 = __builtin_bit_cast(uint32_t, a0);                  \
            uint32_t ua1 = __builtin_bit_cast(uint32_t, a1);                  \
            uint32_t ua2 = __builtin_bit_cast(uint32_t, a2);                  \
            uint32_t ua3 = __builtin_bit_cast(uint32_t, a3);                  \
            uint32_t ub0 = __builtin_bit_cast(uint32_t, b0);                  \
            uint32_t ub1 = __builtin_bit_cast(uint32_t, b1);                  \
            uint32_t ub2 = __builtin_bit_cast(uint32_t, b2);                  \
            uint32_t ub3 = __builtin_bit_cast(uint32_t, b3);                  \
            pk0.u32[i]     = (ua1 & 0xFFFF0000u) | (ua0 >> 16);               \
            pk0.u32[8 + i] = (ua3 & 0xFFFF0000u) | (ua2 >> 16);               \
            pk1.u32[i]     = (ub1 & 0xFFFF0000u) | (ub0 >> 16);               \
            pk1.u32[8 + i] = (ub3 & 0xFFFF0000u) | (ub2 >> 16);               \
        }                                                                     \
        _Pragma("unroll")                                                     \
        for (int b = 0; b < 4; ++b) {                                         \
            O00 = MFMA32(pk0.f[b], CUR[2*b],     O00);                        \
            O01 = MFMA32(pk0.f[b], CUR[2*b + 1], O01);                        \
            O10 = MFMA32(pk1.f[b], CUR[2*b],     O10);                        \
            O11 = MFMA32(pk1.f[b], CUR[2*b + 1], O11);                        \
        }                                                                     \
        S0 = MFMA32(kf0, qf0, zero16());                                      \
        S1 = MFMA32(kf1, qf0, zero16());                                      \
        S2 = MFMA32(kf0, qf1, zero16());                                      \
        S3 = MFMA32(kf1, qf1, zero16());                                      \
    }

    for (int it = 0; it < NIT; it += 2) {
        ATTN_BODY(it,     va, vb);
        ATTN_BODY(it + 1, vb, va);
    }
#undef ATTN_BODY

    // ---- l: lane-pair sum (disjoint key halves, same q); h==0 stores ----
    l0 += __shfl_xor(l0, 32);
    l1 += __shfl_xor(l1, 32);
    const long base = (long)batch * NN;
    if (h == 0 && lane < 32) {
        lws[(size_t)slice * NROWS + base + qb32a * 32 + lane] = l0;
        lws[(size_t)slice * NROWS + base + qb32b * 32 + lane] = l1;
    }

    // ---- O partials -> Opart[slice][row][ch] bf16 (col = 64h+32ct+l31) ----
    #pragma unroll
    for (int qb = 0; qb < 2; ++qb) {
        const int q0 = (qb ? qb32b : qb32a) * 32;
        #pragma unroll
        for (int ct = 0; ct < 2; ++ct) {
            f32x16 Ov = qb ? (ct ? O11 : O10) : (ct ? O01 : O00);
            #pragma unroll
            for (int r = 0; r < 16; ++r) {
                int q = q0 + (r & 3) + 8 * (r >> 2) + 4 * lh;
                Opart[((size_t)slice * NROWS + base + q) * NC + 64 * h + 32 * ct + l31]
                    = (__bf16)Ov[r];
            }
        }
    }
}

// ---------------------------------------------------------------------------
// Kernel 3: combine 4 slice partials + epilogue: out = gamma*(SumO/Suml)+x.
// ---------------------------------------------------------------------------
__global__ __launch_bounds__(256) void combine_kernel(
    const __bf16* __restrict__ Op, const float* __restrict__ lws,
    const float* __restrict__ x, const float* __restrict__ gamma,
    float* __restrict__ out)
{
    __shared__ float gl[32];
    const int  t    = threadIdx.x;
    const long row0 = (long)blockIdx.x * 32;
    if (t < 32) {
        float l = 0.f;
        #pragma unroll
        for (int s = 0; s < NSLICE; ++s) l += lws[(size_t)s * NROWS + row0 + t];
        gl[t] = gamma[0] / l;
    }
    __syncthreads();
    const size_t s1 = (size_t)NROWS * NC;
    #pragma unroll
    for (int i = 0; i < 4; ++i) {
        int idx = t + 256 * i;                 // < 1024 float4 groups
        int r = idx >> 5, c4 = (idx & 31) * 4;
        size_t g = (size_t)(row0 + r) * NC + c4;
        float a0 = 0.f, a1 = 0.f, a2 = 0.f, a3 = 0.f;
        #pragma unroll
        for (int s = 0; s < NSLICE; ++s) {
            union { __bf16 h[4]; uint2 u; } a;
            a.u = *(const uint2*)&Op[s1 * s + g];
            a0 += (float)a.h[0]; a1 += (float)a.h[1];
            a2 += (float)a.h[2]; a3 += (float)a.h[3];
        }
        float sc = gl[r];
        float4 xv = *(const float4*)&x[g];
        float4 o;
        o.x = a0 * sc + xv.x; o.y = a1 * sc + xv.y;
        o.z = a2 * sc + xv.z; o.w = a3 * sc + xv.w;
        *(float4*)&out[g] = o;
    }
}

// ---------------------------------------------------------------------------
extern "C" void kernel_launch(void* const* d_in, const int* in_sizes, int n_in,
                              void* d_out, int out_size, void* d_ws, size_t ws_size,
                              hipStream_t stream) {
    const float* x     = (const float*)d_in[0];
    const float* Wb    = (const float*)d_in[1];
    const float* Wc    = (const float*)d_in[2];
    const float* Wd    = (const float*)d_in[3];
    const float* gamma = (const float*)d_in[4];
    float*       out   = (float*)d_out;

    // ws: qswz .5M | kswz .5M | vswz 4M | wtg 40K | Opart 4x4M bf16 | lws 256K
    __bf16* qswz  = (__bf16*)d_ws;
    __bf16* kswz  = qswz + (size_t)NROWS * NCQ;
    __bf16* vswz  = kswz + (size_t)NROWS * NCQ;
    __bf16* wtg   = vswz + (size_t)NB * NC * NN;
    __bf16* Opart = wtg + 160 * 128;
    float*  lws   = (float*)(Opart + (size_t)NSLICE * NROWS * NC);

    wtrans_kernel <<<160, 128, 0, stream>>>(Wb, Wc, Wd, wtg);
    proj_kernel   <<<NROWS / 32, 256, 0, stream>>>(x, wtg, qswz, kswz, vswz);
    attn_kernel   <<<NB * 64 * 2, 256, 0, stream>>>(qswz, kswz, vswz, Opart, lws);
    combine_kernel<<<NROWS / 32, 256, 0, stream>>>(Opart, lws, x, gamma, out);
}

// Round 12
// 112.767 us; speedup vs baseline: 1.1284x; 1.1284x over previous
//
#include <hip/hip_runtime.h>

// Problem constants: B=4, h=w=z=16 -> N=4096, C=128, Cq=16
#define NB     4
#define NN     4096
#define NC     128
#define NCQ    16
#define NROWS  (NB * NN)      // 16384
#define NSLICE 4
#define NIT    (NN / 64 / NSLICE)   // 16 iterations of 64 keys per slice

typedef __attribute__((ext_vector_type(8)))  __bf16 bf16x8;
typedef __attribute__((ext_vector_type(4)))  float  f32x4;
typedef __attribute__((ext_vector_type(16))) float  f32x16;

#define MFMA16(a,b,c) __builtin_amdgcn_mfma_f32_16x16x32_bf16((a),(b),(c),0,0,0)
#define MFMA32(a,b,c) __builtin_amdgcn_mfma_f32_32x32x16_bf16((a),(b),(c),0,0,0)
#define LOG2E 1.44269504f
// Schraudolph bias for direct-to-bf16 exp2: bits(bf16(2^s)) ~= 128*s + 16248.66
#define SCH_BIAS 16248.66f

__device__ __forceinline__ f32x16 zero16() {
    f32x16 v;
    #pragma unroll
    for (int i = 0; i < 16; ++i) v[i] = 0.f;
    return v;
}

// Swizzled fragment layouts (lane = lh*32 + l31):
//  qswz: [batch][qb32][lane][8]  elem j = (LOG2E * Q)[32*qb32 + l31][ch = 8*lh + j]
//  kswz: [batch][kb32][lane][8]  elem j = K[32*kb32 + l31][ch = 8*lh + j]
//  vswz: [batch][kb16][cg][lane][8]
//        elem j = V^T[ch = 32*cg + l31][key = 16*kb16 + 4*lh + (j&3) + 8*(j>>2)]

// ---------------------------------------------------------------------------
// Kernel 0: W^T precompute -> wtg[160][128] bf16.
// ---------------------------------------------------------------------------
__global__ void wtrans_kernel(const float* __restrict__ Wb,
                              const float* __restrict__ Wc,
                              const float* __restrict__ Wd,
                              __bf16* __restrict__ wtg)
{
    int oc = blockIdx.x;      // 0..159
    int ch = threadIdx.x;     // 0..127
    float v;
    if      (oc < 16) v = Wb[ch * 16  + oc];
    else if (oc < 32) v = Wc[ch * 16  + (oc - 16)];
    else              v = Wd[ch * 128 + (oc - 32)];
    wtg[oc * 128 + ch] = (__bf16)v;
}

// ---------------------------------------------------------------------------
// Kernel 1: projections via MFMA (verified R5-R10 structure; qswz pre-scaled
// by LOG2E so attn's exp needs no multiply).
// ---------------------------------------------------------------------------
__global__ __launch_bounds__(256) void proj_kernel(
    const float* __restrict__ x, const __bf16* __restrict__ wtg,
    __bf16* __restrict__ qswz, __bf16* __restrict__ kswz, __bf16* __restrict__ vswz)
{
    __shared__ __align__(16) __bf16 xsh[32 * 136];   // [row][136]
    __shared__ __align__(16) __bf16 wt [160 * 136];  // [outcol][136]
    __shared__ __align__(16) float  osb[4][16 * 17]; // per-wave transpose buffer

    const int  t    = threadIdx.x;
    const int  lane = t & 63, w = t >> 6;
    const int  q16  = lane & 15, quad = lane >> 4;
    const long row0 = (long)blockIdx.x * 32;
    const int  batch = (int)(row0 >> 12);
    const int  nloc  = (int)(row0 & 4095);
    const int  rh   = w & 1;
    const int  og   = (w >> 1) * 5;

    #pragma unroll
    for (int i = 0; i < 4; ++i) {
        int idx = t + 256 * i;           // < 1024
        int r = idx >> 5, c4 = (idx & 31) * 4;
        float4 xv = *(const float4*)&x[(row0 + r) * NC + c4];
        union { __bf16 h[4]; uint2 u; } cv;
        cv.h[0] = (__bf16)xv.x; cv.h[1] = (__bf16)xv.y;
        cv.h[2] = (__bf16)xv.z; cv.h[3] = (__bf16)xv.w;
        *(uint2*)&xsh[r * 136 + c4] = cv.u;
    }
    #pragma unroll
    for (int i = 0; i < 10; ++i) {
        int idx = t + 256 * i;           // < 2560
        int oc = idx >> 4, seg = idx & 15;
        *(uint4*)&wt[oc * 136 + seg * 8] = ((const uint4*)wtg)[idx];
    }
    __syncthreads();

    bf16x8 xf[4];
    #pragma unroll
    for (int kc = 0; kc < 4; ++kc)
        xf[kc] = *(const bf16x8*)&xsh[(rh * 16 + q16) * 136 + kc * 32 + quad * 8];

    float* osw = osb[w];
    #pragma unroll
    for (int oc_t = 0; oc_t < 5; ++oc_t) {
        const int oset = og + oc_t;
        f32x4 acc = {0.f, 0.f, 0.f, 0.f};
        #pragma unroll
        for (int kc = 0; kc < 4; ++kc) {
            bf16x8 wf = *(const bf16x8*)&wt[(oset * 16 + q16) * 136 + kc * 32 + quad * 8];
            acc = MFMA16(wf, xf[kc], acc);   // D'[oc][row]
        }
        #pragma unroll
        for (int r = 0; r < 4; ++r)
            osw[(quad * 4 + r) * 17 + q16] = acc[r];   // osb[oc16][xrow16]

        if (oset >= 2) {
            int ch_l = lane & 15, lh_t = (lane >> 4) & 1, jh = lane >> 5;
            union { __bf16 h[4]; uint2 u; } cv;
            #pragma unroll
            for (int u2 = 0; u2 < 4; ++u2)
                cv.h[u2] = (__bf16)osw[ch_l * 17 + 8 * jh + 4 * lh_t + u2];
            int kb16 = (nloc >> 4) + rh;
            int cg   = (oset - 2) >> 1;
            int l31v = ((oset - 2) & 1) * 16 + ch_l;
            size_t off = ((((size_t)batch * 256 + kb16) * 4 + cg) << 9)
                       + (size_t)(lh_t * 32 + l31v) * 8 + jh * 4;
            *(uint2*)&vswz[off] = cv.u;
        } else if (lane < 32) {
            int xr = lane & 15, lh_t = lane >> 4;
            const float qsc = (oset == 0) ? LOG2E : 1.f;  // fold log2e into Q
            union { __bf16 h[8]; uint4 u; } cv;
            #pragma unroll
            for (int j = 0; j < 8; ++j)
                cv.h[j] = (__bf16)(osw[(8 * lh_t + j) * 17 + xr] * qsc);
            size_t off = ((((size_t)batch * 128 + (nloc >> 5)) * 64)
                       + (size_t)(lh_t * 32 + rh * 16 + xr)) * 8;
            __bf16* dst = (oset == 0) ? qswz : kswz;
            *(uint4*)&dst[off] = cv.u;
        }
    }
}

// ---------------------------------------------------------------------------
// Kernel 2: flash attention — R10 shape (32-query waves, no spill) with
// transcendental-free softmax:
//   * Schraudolph: bf16 bits of 2^s computed as (int)fma(s,128,SCH_BIAS)
//     (1 fma + 1 cvt + half a lshl_or per score; replaces quarter-rate v_exp)
//   * l via ones-MFMA: MFMA32(pk, ones, Ol) sums P per q-row in-regs —
//     no scalar adds, no cross-lane shuffle (MFMA contracts both lh halves).
// 4 independent waves/block (h = w&1 channel half, slice = sp*2 + (w>>1)),
// split-K x4, XCD swizzle (bid&7 -> batch, slice-pair => K/V L2-resident),
// full next-iter V double-buffer, K prefetch 1 ahead, S-MFMA at loop bottom.
// No LDS, no barriers, no atomics.
// ---------------------------------------------------------------------------
__global__ __launch_bounds__(256, 3) void attn_kernel(
    const __bf16* __restrict__ qswz, const __bf16* __restrict__ kswz,
    const __bf16* __restrict__ vswz, __bf16* __restrict__ Opart,
    float* __restrict__ lws)
{
    const int t    = threadIdx.x;
    const int lane = t & 63, w = t >> 6;
    const int l31 = lane & 31, lh = lane >> 5;
    const int bid   = blockIdx.x;
    const int xcd   = bid & 7;
    const int batch = xcd >> 1;              // constant per XCD
    const int sp    = xcd & 1;               // slice-pair, constant per XCD
    const int qb32  = bid >> 3;              // 0..127
    const int h     = w & 1;                 // channel half
    const int slice = sp * 2 + (w >> 1);     // 0..3
    const int ks0   = slice * (64 * NIT);

    // Q B-frag, fixed: n = q = 32*qb32 + l31, k = ch = 8*lh + j
    const bf16x8 qf = *(const bf16x8*)
        &qswz[(((size_t)batch * 128 + qb32) * 64 + lane) * 8];

    const __bf16* kptr = kswz + ((size_t)batch * 128 + (ks0 >> 5)) * 512 + lane * 8;
    const __bf16* vptr = vswz + ((size_t)batch * 256 + (ks0 >> 4)) * 2048
                       + h * 1024 + lane * 8;

    // ones B-fragment (bf16 1.0 pairs) for the l-summing MFMA
    union { uint32_t u[4]; bf16x8 f; } onesu;
    #pragma unroll
    for (int i = 0; i < 4; ++i) onesu.u[i] = 0x3F803F80u;
    const bf16x8 ones = onesu.f;

    f32x16 O0 = zero16(), O1 = zero16(), Ol = zero16();

    bf16x8 kf0 = *(const bf16x8*)(kptr);
    bf16x8 kf1 = *(const bf16x8*)(kptr + 512);
    bf16x8 va[8], vb[8];
    #pragma unroll
    for (int b = 0; b < 4; ++b) {           // iter-0 V frags (ct = 0,1)
        va[2*b]     = *(const bf16x8*)(vptr + (size_t)(b * 4)     * 512);
        va[2*b + 1] = *(const bf16x8*)(vptr + (size_t)(b * 4 + 1) * 512);
    }
    f32x16 S0 = MFMA32(kf0, qf, zero16());
    f32x16 S1 = MFMA32(kf1, qf, zero16());

#define ATTN_BODY(IT, CUR, NXT)                                               \
    {                                                                         \
        const int itn = ((IT) + 1 < NIT) ? (IT) + 1 : (IT);                   \
        kf0 = *(const bf16x8*)(kptr + (size_t)itn * 1024);                    \
        kf1 = *(const bf16x8*)(kptr + (size_t)itn * 1024 + 512);              \
        _Pragma("unroll")                                                     \
        for (int b = 0; b < 4; ++b) {                                         \
            NXT[2*b]     = *(const bf16x8*)(vptr + (size_t)((itn*4+b)*4)*512);\
            NXT[2*b + 1] = *(const bf16x8*)(vptr + (size_t)((itn*4+b)*4+1)*512);\
        }                                                                     \
        union { uint32_t u32[16]; bf16x8 f[4]; } pk;                          \
        _Pragma("unroll")                                                     \
        for (int i = 0; i < 8; ++i) {                                         \
            int e0 = (int)fmaf(S0[2*i],   128.f, SCH_BIAS);                   \
            int e1 = (int)fmaf(S0[2*i+1], 128.f, SCH_BIAS);                   \
            int e2 = (int)fmaf(S1[2*i],   128.f, SCH_BIAS);                   \
            int e3 = (int)fmaf(S1[2*i+1], 128.f, SCH_BIAS);                   \
            pk.u32[i]     = (uint32_t)((e1 << 16) | e0);                      \
            pk.u32[8 + i] = (uint32_t)((e3 << 16) | e2);                      \
        }                                                                     \
        _Pragma("unroll")                                                     \
        for (int b = 0; b < 4; ++b) {                                         \
            O0 = MFMA32(pk.f[b], CUR[2*b],     O0);                           \
            O1 = MFMA32(pk.f[b], CUR[2*b + 1], O1);                           \
            Ol = MFMA32(pk.f[b], ones,         Ol);                           \
        }                                                                     \
        S0 = MFMA32(kf0, qf, zero16());                                       \
        S1 = MFMA32(kf1, qf, zero16());                                       \
    }

    for (int it = 0; it < NIT; it += 2) {
        ATTN_BODY(it,     va, vb);
        ATTN_BODY(it + 1, vb, va);
    }
#undef ATTN_BODY

    const long base = (long)batch * NN;

    // ---- l: Ol reg r holds sum over ALL this slice's keys for q(r), any col.
    // h==0 wave stores; lanes l31==0 (lh = 0,1) cover the 32 q rows.
    if (h == 0 && l31 == 0) {
        #pragma unroll
        for (int r = 0; r < 16; ++r) {
            int q = qb32 * 32 + (r & 3) + 8 * (r >> 2) + 4 * lh;
            lws[(size_t)slice * NROWS + base + q] = Ol[r];
        }
    }

    // ---- O partial -> Opart[slice][row][ch] bf16 (col = ch = 64h+32ct+l31) --
    #pragma unroll
    for (int ct = 0; ct < 2; ++ct) {
        f32x16 Ov = ct ? O1 : O0;
        #pragma unroll
        for (int r = 0; r < 16; ++r) {
            int q = qb32 * 32 + (r & 3) + 8 * (r >> 2) + 4 * lh;
            Opart[((size_t)slice * NROWS + base + q) * NC + 64 * h + 32 * ct + l31]
                = (__bf16)Ov[r];
        }
    }
}

// ---------------------------------------------------------------------------
// Kernel 3: combine 4 slice partials + epilogue: out = gamma*(SumO/Suml)+x.
// ---------------------------------------------------------------------------
__global__ __launch_bounds__(256) void combine_kernel(
    const __bf16* __restrict__ Op, const float* __restrict__ lws,
    const float* __restrict__ x, const float* __restrict__ gamma,
    float* __restrict__ out)
{
    __shared__ float gl[32];
    const int  t    = threadIdx.x;
    const long row0 = (long)blockIdx.x * 32;
    if (t < 32) {
        float l = 0.f;
        #pragma unroll
        for (int s = 0; s < NSLICE; ++s) l += lws[(size_t)s * NROWS + row0 + t];
        gl[t] = gamma[0] / l;
    }
    __syncthreads();
    const size_t s1 = (size_t)NROWS * NC;
    #pragma unroll
    for (int i = 0; i < 4; ++i) {
        int idx = t + 256 * i;                 // < 1024 float4 groups
        int r = idx >> 5, c4 = (idx & 31) * 4;
        size_t g = (size_t)(row0 + r) * NC + c4;
        float a0 = 0.f, a1 = 0.f, a2 = 0.f, a3 = 0.f;
        #pragma unroll
        for (int s = 0; s < NSLICE; ++s) {
            union { __bf16 h[4]; uint2 u; } a;
            a.u = *(const uint2*)&Op[s1 * s + g];
            a0 += (float)a.h[0]; a1 += (float)a.h[1];
            a2 += (float)a.h[2]; a3 += (float)a.h[3];
        }
        float sc = gl[r];
        float4 xv = *(const float4*)&x[g];
        float4 o;
        o.x = a0 * sc + xv.x; o.y = a1 * sc + xv.y;
        o.z = a2 * sc + xv.z; o.w = a3 * sc + xv.w;
        *(float4*)&out[g] = o;
    }
}

// ---------------------------------------------------------------------------
extern "C" void kernel_launch(void* const* d_in, const int* in_sizes, int n_in,
                              void* d_out, int out_size, void* d_ws, size_t ws_size,
                              hipStream_t stream) {
    const float* x     = (const float*)d_in[0];
    const float* Wb    = (const float*)d_in[1];
    const float* Wc    = (const float*)d_in[2];
    const float* Wd    = (const float*)d_in[3];
    const float* gamma = (const float*)d_in[4];
    float*       out   = (float*)d_out;

    // ws: qswz .5M | kswz .5M | vswz 4M | wtg 40K | Opart 4x4M bf16 | lws 256K
    __bf16* qswz  = (__bf16*)d_ws;
    __bf16* kswz  = qswz + (size_t)NROWS * NCQ;
    __bf16* vswz  = kswz + (size_t)NROWS * NCQ;
    __bf16* wtg   = vswz + (size_t)NB * NC * NN;
    __bf16* Opart = wtg + 160 * 128;
    float*  lws   = (float*)(Opart + (size_t)NSLICE * NROWS * NC);

    wtrans_kernel <<<160, 128, 0, stream>>>(Wb, Wc, Wd, wtg);
    proj_kernel   <<<NROWS / 32, 256, 0, stream>>>(x, wtg, qswz, kswz, vswz);
    attn_kernel   <<<NB * 128 * 2, 256, 0, stream>>>(qswz, kswz, vswz, Opart, lws);
    combine_kernel<<<NROWS / 32, 256, 0, stream>>>(Opart, lws, x, gamma, out);
}